// Round 2
// baseline (720.153 us; speedup 1.0000x reference)
//
#include <hip/hip_runtime.h>
#include <stdint.h>

// HashedEmbeddingBag: out[b][d] = sum_{i<50} weight[(idx[b][i]*P1 + d*P2) % WS]
// WS = 2,000,000; B = 16384; L = 50; D = 128.
//
// R11: R10 structure with the atomic FIXED. R10 post-mortem: atomicAdd on a
// generic float* carved from the smem byte blob did NOT lower to ds_add_f32
// (flat atomic / CAS expansion) -> serial ~1.3K-cycle stalls per element:
// dur 177->671us, VALUBusy 64->12.8%. The accumulator slots acc[g][tag][d]
// (fixed g,d) are THREAD-PRIVATE, so no atomicity is needed at all -- we
// want ds_add_f32 only as a single fire-and-forget LDS-RMW. This version
// emits it directly via inline asm with a raw LDS byte offset (no pointer,
// no addrspace inference): asm("ds_add_f32 %0, %1"). Bank = d%32 -> 2-way
// across a wave = free. "memory" clobber orders it vs region barriers and
// phase-5 readback.
// Structure (unchanged from R10):
//  - 8-bag octet merged into ONE stream/thread; keys (v<<3)|b + rotation
//    copy (v+WS), 8 sentinels.
//  - tile = 2 x 24576-entry bf16 halves (2x48KB), double-buffered: stage
//    region r+1 issued BEFORE sweeping region r; end-of-region barrier
//    drains an already-complete vmcnt. Region 0 staged under the sort.
//    Half base folded into CLr (u' = u + 4*TB preserves tag/addr).
//  - inner loop ~8 VALU + 3 DS per element (key ds_read_b32, gather
//    ds_read_u16, ds_add_f32).
// Accuracy: same bf16 RNE table; f32 adds per (bag,d) in same monotone
// order. No races: staging writes hit the half last read before the
// previous barrier; acc words single-owner per thread.

#define WS       2000000
#define EMB_DIM  128
#define BAG_LEN  50
#define BATCH    16384

#define NBLK     256
#define NTHR     1024
#define BAGS_PB  64
#define NOCT     8                       // 8-bag octets per block
#define EXT8     808                     // 400 + 400 rotation + 8 sentinels
#define THALF    24576                   // entries per tile half (49152 B)
#define NREGD    82                      // 81*24576=1,990,656; last len 9344
#define SBIG     300227u                 // P2 % WS
#define SENT     0x10000000u             // sentinel key; u stays >= LIM

#define OFF_T1   49152                   // tile half 1
#define OFF_ACC  98304                   // 32768 B accumulators
#define OFF_EXT  131072                  // 8*808*4 = 25856 B keys
#define SMEM_SZ  156928

#define GLOAD_LDS16(gp, lp)                                            \
    __builtin_amdgcn_global_load_lds(                                  \
        (const __attribute__((address_space(1))) uint32_t*)(gp),       \
        (__attribute__((address_space(3))) uint32_t*)(lp), 16, 0, 0)

// ---- pre-pass: fp32 table -> bf16 (round-to-nearest-even) ----
__global__ __launch_bounds__(1024) void conv_bf16(
    const float* __restrict__ w, uint16_t* __restrict__ o)
{
    const int i = (blockIdx.x * 1024 + threadIdx.x) * 4;   // 4 floats/thread
    if (i >= WS) return;
    const float4 f = *(const float4*)(w + i);
    uint32_t u0 = __float_as_uint(f.x), u1 = __float_as_uint(f.y);
    uint32_t u2 = __float_as_uint(f.z), u3 = __float_as_uint(f.w);
    ushort4 r;
    r.x = (uint16_t)((u0 + 0x7FFFu + ((u0 >> 16) & 1u)) >> 16);
    r.y = (uint16_t)((u1 + 0x7FFFu + ((u1 >> 16) & 1u)) >> 16);
    r.z = (uint16_t)((u2 + 0x7FFFu + ((u2 >> 16) & 1u)) >> 16);
    r.w = (uint16_t)((u3 + 0x7FFFu + ((u3 >> 16) & 1u)) >> 16);
    *(ushort4*)(o + i) = r;
}

__global__ __launch_bounds__(NTHR, 4) void heb_bf16(
    const uint16_t* __restrict__ wbf,
    const int*      __restrict__ indices,
    float*          __restrict__ out)
{
    __shared__ __align__(16) uint8_t smem[SMEM_SZ];

    const int tid     = threadIdx.x;
    const int d       = tid & 127;
    const int g       = tid >> 7;          // group/octet 0..7 (bags 8g..8g+7)
    const int bagBase = blockIdx.x * BAGS_PB;

    uint16_t* tile0 = (uint16_t*)&smem[0];
    float*    acc   = (float*)&smem[OFF_ACC];
    uint32_t* ext   = (uint32_t*)&smem[OFF_EXT];
    // sort scratch lives in tile half 1 (dead before half 1 is first staged)
    uint32_t* araw  = (uint32_t*)&smem[OFF_T1];           // [64][52]
    uint32_t* S     = (uint32_t*)&smem[OFF_T1 + 16384];   // [64][52]

    // ---- phase 0: stage region 0 into half 0 NOW; hides under sort ----
    for (int s = tid; s < (THALF >> 3); s += NTHR)
        GLOAD_LDS16(wbf + (s << 3), tile0 + (s << 3));

    // ---- phase 1: sentinels, acc zero, hash a = idx*P1 % WS ----
    for (int p = tid; p < NOCT * EXT8; p += NTHR) ext[p] = SENT;
    for (int p = tid; p < BAGS_PB * EMB_DIM; p += NTHR) acc[p] = 0.0f;
    for (int p = tid; p < BAGS_PB * BAG_LEN; p += NTHR) {
        uint32_t b = (uint32_t)p / 50u;
        uint32_t i = (uint32_t)p - b * 50u;
        uint64_t idx = (uint64_t)(uint32_t)indices[bagBase * BAG_LEN + p];
        araw[b * 52 + i] = (uint32_t)((idx * 9824516537ull) % (uint64_t)WS);
    }
    __syncthreads();

    // ---- phase 2a: rank-sort each bag (ties by index) -> S ----
    for (int p = tid; p < BAGS_PB * BAG_LEN; p += NTHR) {
        uint32_t b = (uint32_t)p / 50u;
        uint32_t i = (uint32_t)p - b * 50u;
        uint32_t v = araw[b * 52 + i];
        int rank = 0;
        for (int q = 0; q < BAG_LEN; ++q) {
            uint32_t w = araw[b * 52 + q];
            rank += (w < v || (w == v && q < (int)i)) ? 1 : 0;
        }
        S[b * 52 + rank] = v;
    }
    __syncthreads();

    // ---- phase 2b: 8-way merge per octet via rank composition ----
    for (int p = tid; p < BAGS_PB * BAG_LEN; p += NTHR) {
        uint32_t bag = (uint32_t)p / 50u;
        uint32_t i   = (uint32_t)p - bag * 50u;
        uint32_t oct = bag >> 3, b = bag & 7u;
        uint32_t v = S[bag * 52 + i];
        int rk = (int)i;
        for (uint32_t b2 = 0; b2 < 8u; ++b2) {
            if (b2 == b) continue;
            const uint32_t* T = &S[((oct << 3) + b2) * 52];
            uint32_t key = (b2 < b) ? v + 1u : v;  // tie-break by bag id
            int lo = 0, hi = 50;
            while (lo < hi) {                      // ~6 uniform steps
                int mid = (lo + hi) >> 1;
                bool lt = T[mid] < key;
                lo = lt ? mid + 1 : lo;
                hi = lt ? hi : mid;
            }
            rk += lo;
        }
        uint32_t* eo = ext + oct * EXT8;
        eo[rk]       = (v << 3) | b;                    // first copy
        eo[rk + 400] = ((v + (uint32_t)WS) << 3) | b;   // rotation copy
    }
    __syncthreads();                       // ext final; scratch (half 1) dead

    // ---- phase 3: per-thread single-stream init ----
    const uint32_t c  = ((uint32_t)d * SBIG) % (uint32_t)WS;
    const uint32_t C8 = (uint32_t)(((int)c - WS) * 8);  // 8*(c-WS) mod 2^32
    const uint32_t limit = ((uint32_t)WS - c) << 3;     // count keys < 8*(WS-c)
    const uint32_t* eo = ext + g * EXT8;
    int lo = 0, hi = 400;
    while (lo < hi) {
        int mid = (lo + hi) >> 1;
        bool lt = eo[mid] < limit;
        lo = lt ? mid + 1 : lo;
        hi = lt ? hi : mid;
    }
    const char* kp = (const char*)(eo + lo);
    uint32_t K = *(const uint32_t*)kp;
    // accumulator base: byte offset OFF_ACC + (g*1024 + d)*4; +tag*512B/elem
    const uint32_t accBase =
        (uint32_t)OFF_ACC + (((uint32_t)(g << 10) + (uint32_t)d) << 2);
    __syncthreads();                       // drains stage-0 (long complete)

    // ---- phase 4: region sweep, double-buffered 48KB halves ----
    for (int r = 0; r < NREGD; ++r) {
        // issue next-region staging first: overlaps this region's sweep;
        // target half was last read before the barrier ending iter r-1.
        if (r + 1 < NREGD) {
            const int lo2  = (r + 1) * THALF;
            const int len2 = (THALF < WS - lo2) ? THALF : (WS - lo2);
            uint16_t* dst = (uint16_t*)&smem[((r + 1) & 1) ? OFF_T1 : 0];
            for (int s = tid; s < (len2 >> 3); s += NTHR)
                GLOAD_LDS16(wbf + lo2 + (s << 3), dst + (s << 3));
        }

        const int rlo = r * THALF;
        const int len = (THALF < WS - rlo) ? THALF : (WS - rlo);
        const uint32_t TB4 = (r & 1) ? ((uint32_t)OFF_T1 << 2) : 0u;
        const uint32_t CLr = C8 + TB4 - ((uint32_t)rlo << 3);
        const uint32_t LIM = ((uint32_t)len << 3) + TB4;

        uint32_t u = K + CLr;              // 8*(pos-rlo) + tag + TB4
        while (u < LIM) {
            const uint32_t baddr = (u >> 2) & ~1u;        // byte into tile
            kp += 4;
            const uint32_t Kn = *(const uint32_t*)kp;     // next key early
            const uint32_t raw = *(const uint16_t*)(smem + baddr);
            const float v = __uint_as_float(raw << 16);   // bf16 -> f32
            // thread-private (bag,d) slot: fire-and-forget LDS RMW.
            // Raw byte offset in a VGPR -> guaranteed ds_add_f32 (no
            // addrspace inference, no CAS expansion -- R10's 3.8x bug).
            asm volatile("ds_add_f32 %0, %1"
                         :
                         : "v"(accBase + ((u & 7u) << 9)), "v"(v)
                         : "memory");
            K = Kn;
            u = Kn + CLr;
        }
        __syncthreads();                   // next half staged + this half done
    }

    // ---- phase 5: coalesced output (bag = 8g + b) ----
#pragma unroll
    for (int b = 0; b < 8; ++b)
        out[(size_t)(bagBase + (g << 3) + b) * EMB_DIM + d] =
            acc[((g << 3) + b) * EMB_DIM + d];
}

// ---- fallback (ws too small): R7's proven fp32 single-tile kernel ----
#define RSIZE_FB 32768
#define NREG_FB  62
#define EXT_N    104
#define SENT4    0x10000000u

__global__ __launch_bounds__(NTHR, 4) void heb_single(
    const float* __restrict__ weight,
    const int*   __restrict__ indices,
    float*       __restrict__ out)
{
    __shared__ __align__(16) float tile[RSIZE_FB];
    __shared__ uint32_t ext4[BAGS_PB][EXT_N];
    const int tid = threadIdx.x, d = tid & 127, bag_lo = tid >> 7;
    const int bagBase = blockIdx.x * BAGS_PB;
    uint32_t* araw = (uint32_t*)&tile[0];
    for (int p = tid; p < BAGS_PB * BAG_LEN; p += NTHR) {
        uint32_t g = (uint32_t)p / 50u, i = (uint32_t)p - g * 50u;
        uint64_t idx = (uint64_t)(uint32_t)indices[bagBase * BAG_LEN + p];
        araw[g * 52 + i] = (uint32_t)((idx * 9824516537ull) % (uint64_t)WS);
    }
    __syncthreads();
    for (int p = tid; p < BAGS_PB * BAG_LEN; p += NTHR) {
        uint32_t g = (uint32_t)p / 50u, i = (uint32_t)p - g * 50u;
        uint32_t v = araw[g * 52 + i];
        int rank = 0;
        for (int q = 0; q < BAG_LEN; ++q) {
            uint32_t w = araw[g * 52 + q];
            rank += (w < v || (w == v && q < (int)i)) ? 1 : 0;
        }
        ext4[g][rank] = v << 2;
        ext4[g][rank + 50] = (v + (uint32_t)WS) << 2;
    }
    for (int p = tid; p < BAGS_PB * 4; p += NTHR)
        ext4[p >> 2][100 + (p & 3)] = SENT4;
    __syncthreads();
    const uint32_t c = ((uint32_t)d * SBIG) % (uint32_t)WS;
    const uint32_t C4 = (uint32_t)(((int)c - WS) * 4);
    const uint32_t wmc4 = ((uint32_t)WS - c) << 2;
    uint32_t t4[8], h4[8]; float sm[8];
#pragma unroll
    for (int k = 0; k < 8; ++k) {
        const uint32_t* eg = &ext4[(bag_lo << 3) + k][0];
        int nlow = 0;
        for (int q = 0; q < BAG_LEN; ++q) nlow += (eg[q] < wmc4) ? 1 : 0;
        t4[k] = (uint32_t)nlow << 2; h4[k] = eg[nlow] + C4; sm[k] = 0.0f;
    }
    for (int r = 0; r < NREG_FB; ++r) {
        const int lo = r * RSIZE_FB;
        const int len = (RSIZE_FB < WS - lo) ? RSIZE_FB : (WS - lo);
        __syncthreads();
        for (int s = tid; s < (len >> 2); s += NTHR)
            GLOAD_LDS16(weight + lo + (s << 2), &tile[s << 2]);
        __syncthreads();
        const uint32_t lo4 = ((uint32_t)lo) << 2;
        const uint32_t hi4 = (r == NREG_FB - 1) ? (uint32_t)(4 * WS)
                                                : lo4 + ((uint32_t)RSIZE_FB << 2);
        const char* tb = (const char*)&tile[0];
#pragma unroll
        for (int k = 0; k < 8; ++k) {
            const char* eg = (const char*)&ext4[(bag_lo << 3) + k][0];
            uint32_t t_ = t4[k], h_ = h4[k]; float s_ = sm[k];
            while (h_ < hi4) {
                s_ += *(const float*)(tb + (h_ - lo4));
                t_ += 4u;
                h_ = *(const uint32_t*)(eg + t_) + C4;
            }
            t4[k] = t_; h4[k] = h_; sm[k] = s_;
        }
    }
#pragma unroll
    for (int k = 0; k < 8; ++k)
        out[(size_t)(bagBase + (bag_lo << 3) + k) * EMB_DIM + d] = sm[k];
}

extern "C" void kernel_launch(void* const* d_in, const int* in_sizes, int n_in,
                              void* d_out, int out_size, void* d_ws, size_t ws_size,
                              hipStream_t stream)
{
    const float* weight  = (const float*)d_in[0];   // [2,000,000] fp32
    const int*   indices = (const int*)d_in[1];     // [16384*50] int
    float*       out     = (float*)d_out;           // [16384*128] fp32

    if (ws_size >= (size_t)WS * sizeof(uint16_t)) {
        uint16_t* wbf = (uint16_t*)d_ws;
        conv_bf16<<<(WS / 4 + 1023) / 1024, 1024, 0, stream>>>(weight, wbf);
        heb_bf16<<<NBLK, NTHR, 0, stream>>>(wbf, indices, out);
    } else {
        heb_single<<<NBLK, NTHR, 0, stream>>>(weight, indices, out);
    }
}

// Round 3
// 230.022 us; speedup vs baseline: 3.1308x; 3.1308x over previous
//
#include <hip/hip_runtime.h>
#include <stdint.h>

// HashedEmbeddingBag: out[b][d] = sum_{i<50} weight[(idx[b][i]*P1 + d*P2) % WS]
// WS = 2,000,000; B = 16384; L = 50; D = 128.
//
// R12: pair-merged streams + REGISTER accumulators + dbuf staging.
// R11 post-mortem: guaranteed ds_add_f32 (inline asm) was byte-identical
// to R10's atomicAdd (670us, VALU 12%) -> R10's "atomic lowering" theory
// FALSE. The ds_add_f32 itself is the wall: ~14.4K RMW wave-instrs/CU
// x ~80cy LDS-pipe occupancy each ~= the extra 1.2M cycles. LDS atomic
// RMW ~ 15x a ds_read; never in the per-element path. Revert to register
// accumulation (R9-proven, 177us).
// R9's wall was VALUBusy 64% (~113us), dominated by the 4-way merge's
// 12-op cmp/cndmask/add tag routing. R12 rebalances:
//  - k=2 pair-merge: 32 pair-streams/block, 4 streams/thread, tag = 1 bit.
//    Routing = 1 cmp + 2 cndmask + 2 add (5 ops, was 12). Wave-iter
//    inflation rises 810 -> ~1300 but each iter is ~13 VALU (was ~19).
//  - keys stored pre-shifted (v<<1)|b (+rotation copy (v+WS)<<1|b):
//    gather byte addr = u & ~1 with tile-half base folded into CLr;
//    no shifts in the loop.
//  - dbuf 2x64KB bf16 halves (62 regions), stage r+1 issued BEFORE
//    sweeping r (R10/R11-proven machinery): staging + barrier drains
//    hidden. Region 0 staged under the sort phases.
//  - output straight from registers (no LDS readback).
// Model: VALU ~60us/SIMD, LDS pipe ~95-110us/CU -> predict 115-145us.
// Accuracy: same bf16 RNE table, f32 adds in monotone position order
// (R9 family, absmax 0.25 vs threshold 0.71). No races: staging writes
// target the half last read before the prior barrier (barrier's
// vmcnt(0)+lgkmcnt(0) drain orders both directions).

#define WS       2000000
#define EMB_DIM  128
#define BAG_LEN  50
#define BATCH    16384

#define NBLK     256
#define NTHR     1024
#define BAGS_PB  64
#define NPAIR    32                      // bag-pair streams per block
#define SPT      4                       // streams per thread
#define EXTP     208                     // 100 + 100 rotation + 8 sentinels
#define THALF    32768                   // entries per tile half (65536 B)
#define NREGD    62                      // 61*32768=1,998,848; last len 1152
#define SBIG     300227u                 // P2 % WS
#define SENT     0x10000000u             // sentinel key; u stays >= LIM

#define OFF_T1   65536                   // tile half 1
#define OFF_EXT  131072                  // 32*208*4 = 26624 B keys
#define SMEM_SZ  157696

#define GLOAD_LDS16(gp, lp)                                            \
    __builtin_amdgcn_global_load_lds(                                  \
        (const __attribute__((address_space(1))) uint32_t*)(gp),       \
        (__attribute__((address_space(3))) uint32_t*)(lp), 16, 0, 0)

// ---- pre-pass: fp32 table -> bf16 (round-to-nearest-even) ----
__global__ __launch_bounds__(1024) void conv_bf16(
    const float* __restrict__ w, uint16_t* __restrict__ o)
{
    const int i = (blockIdx.x * 1024 + threadIdx.x) * 4;   // 4 floats/thread
    if (i >= WS) return;
    const float4 f = *(const float4*)(w + i);
    uint32_t u0 = __float_as_uint(f.x), u1 = __float_as_uint(f.y);
    uint32_t u2 = __float_as_uint(f.z), u3 = __float_as_uint(f.w);
    ushort4 r;
    r.x = (uint16_t)((u0 + 0x7FFFu + ((u0 >> 16) & 1u)) >> 16);
    r.y = (uint16_t)((u1 + 0x7FFFu + ((u1 >> 16) & 1u)) >> 16);
    r.z = (uint16_t)((u2 + 0x7FFFu + ((u2 >> 16) & 1u)) >> 16);
    r.w = (uint16_t)((u3 + 0x7FFFu + ((u3 >> 16) & 1u)) >> 16);
    *(ushort4*)(o + i) = r;
}

__global__ __launch_bounds__(NTHR, 4) void heb_bf16(
    const uint16_t* __restrict__ wbf,
    const int*      __restrict__ indices,
    float*          __restrict__ out)
{
    __shared__ __align__(16) uint8_t smem[SMEM_SZ];

    const int tid     = threadIdx.x;
    const int d       = tid & 127;
    const int g       = tid >> 7;          // group 0..7 (pairs 4g..4g+3)
    const int bagBase = blockIdx.x * BAGS_PB;

    uint16_t* tile0 = (uint16_t*)&smem[0];
    uint32_t* ext   = (uint32_t*)&smem[OFF_EXT];
    // sort scratch lives in tile half 1 (dead before half 1 is first staged
    // -- staging of region 1 is issued only after the phase-3 barrier)
    uint32_t* araw  = (uint32_t*)&smem[OFF_T1];           // [64][52]
    uint32_t* S     = (uint32_t*)&smem[OFF_T1 + 13312];   // [64][52]

    // ---- phase 0: stage region 0 into half 0 NOW; hides under sort ----
    for (int s = tid; s < (THALF >> 3); s += NTHR)
        GLOAD_LDS16(wbf + (s << 3), tile0 + (s << 3));

    // ---- phase 1: sentinel-fill ext; hash a = idx*P1 % WS ----
    for (int p = tid; p < NPAIR * EXTP; p += NTHR) ext[p] = SENT;
    for (int p = tid; p < BAGS_PB * BAG_LEN; p += NTHR) {
        uint32_t b = (uint32_t)p / 50u;
        uint32_t i = (uint32_t)p - b * 50u;
        uint64_t idx = (uint64_t)(uint32_t)indices[bagBase * BAG_LEN + p];
        araw[b * 52 + i] = (uint32_t)((idx * 9824516537ull) % (uint64_t)WS);
    }
    __syncthreads();

    // ---- phase 2a: rank-sort each bag (ties by index) -> S ----
    for (int p = tid; p < BAGS_PB * BAG_LEN; p += NTHR) {
        uint32_t b = (uint32_t)p / 50u;
        uint32_t i = (uint32_t)p - b * 50u;
        uint32_t v = araw[b * 52 + i];
        int rank = 0;
        for (int q = 0; q < BAG_LEN; ++q) {
            uint32_t w = araw[b * 52 + q];
            rank += (w < v || (w == v && q < (int)i)) ? 1 : 0;
        }
        S[b * 52 + rank] = v;
    }
    __syncthreads();

    // ---- phase 2b: 2-way merge per pair via one binary search ----
    for (int p = tid; p < BAGS_PB * BAG_LEN; p += NTHR) {
        uint32_t bag = (uint32_t)p / 50u;
        uint32_t i   = (uint32_t)p - bag * 50u;
        uint32_t pr  = bag >> 1, b = bag & 1u;
        uint32_t v = S[bag * 52 + i];
        const uint32_t* T = &S[(bag ^ 1u) * 52];
        uint32_t key = b ? v + 1u : v;         // tie-break by bag id
        int lo = 0, hi = 50;
        while (lo < hi) {                      // ~6 uniform steps
            int mid = (lo + hi) >> 1;
            bool lt = T[mid] < key;
            lo = lt ? mid + 1 : lo;
            hi = lt ? hi : mid;
        }
        uint32_t* eo = ext + pr * EXTP;
        int rk = (int)i + lo;
        eo[rk]       = (v << 1) | b;                    // first copy
        eo[rk + 100] = ((v + (uint32_t)WS) << 1) | b;   // rotation copy
    }
    __syncthreads();                       // ext final; scratch (half 1) dead

    // ---- phase 3: per-thread 4-stream init ----
    const uint32_t c  = ((uint32_t)d * SBIG) % (uint32_t)WS;
    const uint32_t C2 = (uint32_t)(((int)c - WS) * 2);  // 2*(c-WS) mod 2^32
    const uint32_t limit2 = ((uint32_t)WS - c) << 1;    // keys < 2*(WS-c)

    const char* kp4[SPT];
    uint32_t    K4[SPT];
    float       s0r[SPT], s1r[SPT];
#pragma unroll
    for (int qi = 0; qi < SPT; ++qi) {
        const uint32_t* eo = ext + ((g << 2) + qi) * EXTP;
        int lo = 0, hi = 100;
        while (lo < hi) {
            int mid = (lo + hi) >> 1;
            bool lt = eo[mid] < limit2;
            lo = lt ? mid + 1 : lo;
            hi = lt ? hi : mid;
        }
        kp4[qi] = (const char*)(eo + lo);
        K4[qi]  = eo[lo];
        s0r[qi] = 0.0f; s1r[qi] = 0.0f;
    }
    __syncthreads();                       // drains stage-0 (long complete)

    // ---- phase 4: region sweep, double-buffered 64KB halves ----
    for (int r = 0; r < NREGD; ++r) {
        // issue next-region staging first: overlaps this region's sweep;
        // target half was last read before the barrier ending iter r-1.
        if (r + 1 < NREGD) {
            const int lo2  = (r + 1) * THALF;
            const int len2 = (THALF < WS - lo2) ? THALF : (WS - lo2);
            uint16_t* dst = (uint16_t*)&smem[((r + 1) & 1) ? OFF_T1 : 0];
            for (int s = tid; s < (len2 >> 3); s += NTHR)
                GLOAD_LDS16(wbf + lo2 + (s << 3), dst + (s << 3));
        }

        const int rlo = r * THALF;
        const int len = (THALF < WS - rlo) ? THALF : (WS - rlo);
        const uint32_t TB  = (r & 1) ? (uint32_t)OFF_T1 : 0u;
        const uint32_t CLr = C2 + TB - ((uint32_t)rlo << 1);
        const uint32_t LIM = ((uint32_t)len << 1) + TB;

#pragma unroll
        for (int qi = 0; qi < SPT; ++qi) {
            const char* kp = kp4[qi];
            uint32_t K_ = K4[qi];
            float s0 = s0r[qi], s1 = s1r[qi];
            uint32_t u = K_ + CLr;         // 2*(pos-rlo) + tag + TB
            while (u < LIM) {
                const uint32_t raw =
                    *(const uint16_t*)(smem + (u & ~1u)); // ds_read_u16
                kp += 4;
                const uint32_t Kn = *(const uint32_t*)kp; // next key early
                const float v = __uint_as_float(raw << 16);
                const bool odd = (u & 1u) != 0u;          // 1-bit routing
                s0 += odd ? 0.0f : v;
                s1 += odd ? v : 0.0f;
                K_ = Kn;
                u  = Kn + CLr;
            }
            kp4[qi] = kp; K4[qi] = K_;
            s0r[qi] = s0; s1r[qi] = s1;
        }
        __syncthreads();                   // next half staged + this half done
    }

    // ---- phase 5: output straight from registers (bag = 8g + 2qi + t) ----
#pragma unroll
    for (int qi = 0; qi < SPT; ++qi) {
        const int bag = (g << 3) + (qi << 1);
        out[(size_t)(bagBase + bag) * EMB_DIM + d]     = s0r[qi];
        out[(size_t)(bagBase + bag + 1) * EMB_DIM + d] = s1r[qi];
    }
}

// ---- fallback (ws too small): R7's proven fp32 single-tile kernel ----
#define RSIZE_FB 32768
#define NREG_FB  62
#define EXT_N    104
#define SENT4    0x10000000u

__global__ __launch_bounds__(NTHR, 4) void heb_single(
    const float* __restrict__ weight,
    const int*   __restrict__ indices,
    float*       __restrict__ out)
{
    __shared__ __align__(16) float tile[RSIZE_FB];
    __shared__ uint32_t ext4[BAGS_PB][EXT_N];
    const int tid = threadIdx.x, d = tid & 127, bag_lo = tid >> 7;
    const int bagBase = blockIdx.x * BAGS_PB;
    uint32_t* araw = (uint32_t*)&tile[0];
    for (int p = tid; p < BAGS_PB * BAG_LEN; p += NTHR) {
        uint32_t g = (uint32_t)p / 50u, i = (uint32_t)p - g * 50u;
        uint64_t idx = (uint64_t)(uint32_t)indices[bagBase * BAG_LEN + p];
        araw[g * 52 + i] = (uint32_t)((idx * 9824516537ull) % (uint64_t)WS);
    }
    __syncthreads();
    for (int p = tid; p < BAGS_PB * BAG_LEN; p += NTHR) {
        uint32_t g = (uint32_t)p / 50u, i = (uint32_t)p - g * 50u;
        uint32_t v = araw[g * 52 + i];
        int rank = 0;
        for (int q = 0; q < BAG_LEN; ++q) {
            uint32_t w = araw[g * 52 + q];
            rank += (w < v || (w == v && q < (int)i)) ? 1 : 0;
        }
        ext4[g][rank] = v << 2;
        ext4[g][rank + 50] = (v + (uint32_t)WS) << 2;
    }
    for (int p = tid; p < BAGS_PB * 4; p += NTHR)
        ext4[p >> 2][100 + (p & 3)] = SENT4;
    __syncthreads();
    const uint32_t c = ((uint32_t)d * SBIG) % (uint32_t)WS;
    const uint32_t C4 = (uint32_t)(((int)c - WS) * 4);
    const uint32_t wmc4 = ((uint32_t)WS - c) << 2;
    uint32_t t4[8], h4[8]; float sm[8];
#pragma unroll
    for (int k = 0; k < 8; ++k) {
        const uint32_t* eg = &ext4[(bag_lo << 3) + k][0];
        int nlow = 0;
        for (int q = 0; q < BAG_LEN; ++q) nlow += (eg[q] < wmc4) ? 1 : 0;
        t4[k] = (uint32_t)nlow << 2; h4[k] = eg[nlow] + C4; sm[k] = 0.0f;
    }
    for (int r = 0; r < NREG_FB; ++r) {
        const int lo = r * RSIZE_FB;
        const int len = (RSIZE_FB < WS - lo) ? RSIZE_FB : (WS - lo);
        __syncthreads();
        for (int s = tid; s < (len >> 2); s += NTHR)
            GLOAD_LDS16(weight + lo + (s << 2), &tile[s << 2]);
        __syncthreads();
        const uint32_t lo4 = ((uint32_t)lo) << 2;
        const uint32_t hi4 = (r == NREG_FB - 1) ? (uint32_t)(4 * WS)
                                                : lo4 + ((uint32_t)RSIZE_FB << 2);
        const char* tb = (const char*)&tile[0];
#pragma unroll
        for (int k = 0; k < 8; ++k) {
            const char* eg = (const char*)&ext4[(bag_lo << 3) + k][0];
            uint32_t t_ = t4[k], h_ = h4[k]; float s_ = sm[k];
            while (h_ < hi4) {
                s_ += *(const float*)(tb + (h_ - lo4));
                t_ += 4u;
                h_ = *(const uint32_t*)(eg + t_) + C4;
            }
            t4[k] = t_; h4[k] = h_; sm[k] = s_;
        }
    }
#pragma unroll
    for (int k = 0; k < 8; ++k)
        out[(size_t)(bagBase + (bag_lo << 3) + k) * EMB_DIM + d] = sm[k];
}

extern "C" void kernel_launch(void* const* d_in, const int* in_sizes, int n_in,
                              void* d_out, int out_size, void* d_ws, size_t ws_size,
                              hipStream_t stream)
{
    const float* weight  = (const float*)d_in[0];   // [2,000,000] fp32
    const int*   indices = (const int*)d_in[1];     // [16384*50] int
    float*       out     = (float*)d_out;           // [16384*128] fp32

    if (ws_size >= (size_t)WS * sizeof(uint16_t)) {
        uint16_t* wbf = (uint16_t*)d_ws;
        conv_bf16<<<(WS / 4 + 1023) / 1024, 1024, 0, stream>>>(weight, wbf);
        heb_bf16<<<NBLK, NTHR, 0, stream>>>(wbf, indices, out);
    } else {
        heb_single<<<NBLK, NTHR, 0, stream>>>(weight, indices, out);
    }
}